// Round 2
// baseline (32645.322 us; speedup 1.0000x reference)
//
#include <hip/hip_runtime.h>

typedef unsigned short u16;
typedef unsigned int u32;
typedef __attribute__((ext_vector_type(8))) short bf16x8;
typedef __attribute__((ext_vector_type(4))) float f32x4;

#define MFMA16(a, b, c) __builtin_amdgcn_mfma_f32_16x16x32_bf16((a), (b), (c), 0, 0, 0)

__device__ __forceinline__ u16 f2bf(float f) {
    union { float f; u32 u; } v; v.f = f;
    u32 r = v.u + 0x7FFFu + ((v.u >> 16) & 1u);
    return (u16)(r >> 16);
}
__device__ __forceinline__ float bf2f(u32 lo16) {
    return __uint_as_float(lo16 << 16);
}
__device__ __forceinline__ float sigmoidf_(float x) {
    return 1.0f / (1.0f + __expf(-x));
}
__device__ __forceinline__ float tanhf_(float x) {
    float e = __expf(-2.0f * x);
    return (1.0f - e) / (1.0f + e);
}

// ---------------- mask: mask[row] = any(X[row, :512] != 0) ----------------
__global__ void mask_kernel(const float* __restrict__ X, int* __restrict__ mask) {
    int row = blockIdx.x;
    int lane = threadIdx.x;
    const float* r = X + (size_t)row * 512;
    int nz = 0;
    #pragma unroll
    for (int i = 0; i < 8; ++i) nz |= (r[lane + 64 * i] != 0.0f);
    nz = __any(nz);
    if (lane == 0) mask[row] = nz ? 1 : 0;
}

// ---------------- cast fp32 -> bf16 (4 elems/thread) ----------------
__global__ void cast_bf16_kernel(const float* __restrict__ in, u16* __restrict__ out, int n) {
    int i = (blockIdx.x * blockDim.x + threadIdx.x) * 4;
    if (i + 3 < n) {
        float4 v = *(const float4*)(in + i);
        u32 a = (u32)f2bf(v.x) | ((u32)f2bf(v.y) << 16);
        u32 b = (u32)f2bf(v.z) | ((u32)f2bf(v.w) << 16);
        *(uint2*)(out + i) = make_uint2(a, b);
    }
}

// ---------------- transpose + cast: in fp32 [K][N] -> out bf16 [N][K] ----------------
__global__ void transpose_cast_kernel(const float* __restrict__ in, u16* __restrict__ out,
                                      int K, int N) {
    __shared__ float tile[32][33];
    int k0 = blockIdx.y * 32, n0 = blockIdx.x * 32;
    int tx = threadIdx.x, ty = threadIdx.y;
    #pragma unroll
    for (int i = ty; i < 32; i += 8)
        tile[i][tx] = in[(size_t)(k0 + i) * N + (n0 + tx)];
    __syncthreads();
    #pragma unroll
    for (int i = ty; i < 32; i += 8)
        out[(size_t)(n0 + i) * K + (k0 + tx)] = f2bf(tile[tx][i]);
}

// ---------------- GEMM: C[M][2048] = A[M][K](bf16) @ Bt[N][K](bf16)^T + bias (fp16 out) ----
// block 256 thr = 4 waves; block tile 64(M) x 64(N); wave = 16-row strip.
__global__ __launch_bounds__(256) void gemm_xz_kernel(
        const u16* __restrict__ A, const u16* __restrict__ Bt,
        const float* __restrict__ bias, _Float16* __restrict__ C, int K) {
    const int N = 2048;
    int w = threadIdx.x >> 6, lane = threadIdx.x & 63;
    int q = lane >> 4, col = lane & 15;
    int m0 = blockIdx.x * 64 + w * 16;
    int n0 = blockIdx.y * 64;

    const u16* arow = A + (size_t)(m0 + col) * K + q * 8;
    f32x4 acc[4];
    #pragma unroll
    for (int nt = 0; nt < 4; ++nt) acc[nt] = (f32x4){0.f, 0.f, 0.f, 0.f};

    for (int kc = 0; kc < K; kc += 32) {
        bf16x8 a = *(const bf16x8*)(arow + kc);
        #pragma unroll
        for (int nt = 0; nt < 4; ++nt) {
            bf16x8 b = *(const bf16x8*)(Bt + (size_t)(n0 + nt * 16 + col) * K + kc + q * 8);
            acc[nt] = MFMA16(a, b, acc[nt]);
        }
    }
    int row = m0 + q * 4;
    #pragma unroll
    for (int nt = 0; nt < 4; ++nt) {
        int c_ = n0 + nt * 16 + col;
        float bs = bias[c_];
        #pragma unroll
        for (int r = 0; r < 4; ++r)
            C[(size_t)(row + r) * N + c_] = (_Float16)(acc[nt][r] + bs);
    }
}

// ---------------- LSTM recurrence, one direction+batch-group per block ----------------
// grid (4 batch-groups, 2 dirs), block 1024 = 16 waves.
// Wave w owns d-slice [w*32, w*32+32); computes z cols {g*512 + d-slice} for g=0..3.
// c,h state in registers (lane owns 8 (m,d) cells); h published bf16 via double-buffered LDS.
__global__ __launch_bounds__(1024) void lstm_rec_kernel(
        const _Float16* __restrict__ xz_f, const _Float16* __restrict__ xz_b,
        const u16* __restrict__ Ut_f, const u16* __restrict__ Ut_b,
        const int* __restrict__ mask,
        u16* __restrict__ y_bf,     // layer1: [16384][1024] bf16 (null for layer2)
        float* __restrict__ y_f32,  // layer2: d_out H [16384][1024] (null for layer1)
        float* __restrict__ hc_out) // layer2: hidden at +0, cell at +65536 (null for layer1)
{
    const int T = 256;
    const int PADD = 520;  // 512 + 8 pad (kills 16-way LDS bank conflict on a-frag reads)
    int bg = blockIdx.x, dir = blockIdx.y;
    int tid = threadIdx.x;
    int w = tid >> 6, lane = tid & 63, q = lane >> 4, col = lane & 15;

    const _Float16* xz = dir ? xz_b : xz_f;
    const u16* Ut = dir ? Ut_b : Ut_f;

    alignas(16) __shared__ u16 hbuf[2][16][520];
    {
        u32* hb = (u32*)hbuf;  // 2*16*520/2 = 8320 uints
        for (int i = tid; i < 8320; i += 1024) hb[i] = 0;
    }
    float creg[2][4], hreg[2][4];
    #pragma unroll
    for (int s = 0; s < 2; ++s)
        #pragma unroll
        for (int r = 0; r < 4; ++r) { creg[s][r] = 0.f; hreg[s][r] = 0.f; }
    __syncthreads();

    int dbase = w * 32;

    for (int it = 0; it < T; ++it) {
        int t = dir ? (T - 1 - it) : it;
        int p = it & 1;

        f32x4 acc[4][2];
        #pragma unroll
        for (int g = 0; g < 4; ++g)
            #pragma unroll
            for (int s = 0; s < 2; ++s) acc[g][s] = (f32x4){0.f, 0.f, 0.f, 0.f};

        for (int kc = 0; kc < 512; kc += 32) {
            bf16x8 a = *(const bf16x8*)(&hbuf[p][col][kc + q * 8]);
            #pragma unroll
            for (int g = 0; g < 4; ++g)
                #pragma unroll
                for (int s = 0; s < 2; ++s) {
                    const u16* bp = Ut + (size_t)(g * 512 + dbase + s * 16 + col) * 512 + kc + q * 8;
                    bf16x8 b = *(const bf16x8*)bp;
                    acc[g][s] = MFMA16(a, b, acc[g][s]);
                }
        }

        // gates + state update (all in registers), publish h to other LDS buffer
        #pragma unroll
        for (int s = 0; s < 2; ++s) {
            int d = dbase + s * 16 + col;
            #pragma unroll
            for (int r = 0; r < 4; ++r) {
                int b = bg * 16 + q * 4 + r;
                size_t zrow = ((size_t)b * T + t) * 2048;
                float zi = acc[0][s][r] + (float)xz[zrow + d];
                float zf = acc[1][s][r] + (float)xz[zrow + 512 + d];
                float zg = acc[2][s][r] + (float)xz[zrow + 1024 + d];
                float zo = acc[3][s][r] + (float)xz[zrow + 1536 + d];
                float ig = sigmoidf_(zi);
                float fg = sigmoidf_(zf);
                float gg = tanhf_(zg);
                float og = sigmoidf_(zo);
                float cn = fg * creg[s][r] + ig * gg;
                float hn = og * tanhf_(cn);
                if (mask[b * T + t]) { creg[s][r] = cn; hreg[s][r] = hn; }
                hbuf[1 - p][q * 4 + r][d] = f2bf(hreg[s][r]);
            }
        }
        __syncthreads();

        // emit y[t] (= h after step t) from the freshly written buffer, coalesced
        {
            const u32* src = (const u32*)(&hbuf[1 - p][0][0]);
            #pragma unroll
            for (int u = tid; u < 4096; u += 1024) {
                int rrow = u >> 8;      // 0..15
                int cpos = u & 255;     // uint column (2 bf16 each)
                u32 v = src[rrow * (PADD / 2) + cpos];
                int b = bg * 16 + rrow;
                size_t base = ((size_t)b * T + t) * 1024 + dir * 512 + cpos * 2;
                if (y_bf) {
                    *(u32*)(y_bf + base) = v;
                } else {
                    float2 f2;
                    f2.x = bf2f(v & 0xFFFFu);
                    f2.y = bf2f(v >> 16);
                    *(float2*)(y_f32 + base) = f2;
                }
            }
        }
    }

    if (hc_out) {
        #pragma unroll
        for (int s = 0; s < 2; ++s) {
            int d = dbase + s * 16 + col;
            #pragma unroll
            for (int r = 0; r < 4; ++r) {
                int b = bg * 16 + q * 4 + r;
                hc_out[(size_t)b * 1024 + dir * 512 + d] = hreg[s][r];
                hc_out[65536 + (size_t)b * 1024 + dir * 512 + d] = creg[s][r];
            }
        }
    }
}

extern "C" void kernel_launch(void* const* d_in, const int* in_sizes, int n_in,
                              void* d_out, int out_size, void* d_ws, size_t ws_size,
                              hipStream_t stream) {
    const float* X   = (const float*)d_in[0];
    const float* Wf1 = (const float*)d_in[1];
    const float* Uf1 = (const float*)d_in[2];
    const float* bf1 = (const float*)d_in[3];
    const float* Wb1 = (const float*)d_in[4];
    const float* Ub1 = (const float*)d_in[5];
    const float* bb1 = (const float*)d_in[6];
    const float* Wf2 = (const float*)d_in[7];
    const float* Uf2 = (const float*)d_in[8];
    const float* bf2 = (const float*)d_in[9];
    const float* Wb2 = (const float*)d_in[10];
    const float* Ub2 = (const float*)d_in[11];
    const float* bb2 = (const float*)d_in[12];
    float* out = (float*)d_out;

    // ---- scratch carved out of d_out's H region (67.1 MB, dead until lstm_rec2) ----
    // y1bf [16384][1024] bf16 = 33.55 MB at byte 0; Xbf [16384][512] bf16 = 16.78 MB after.
    // Both are fully consumed by the layer-2 GEMMs, which complete (stream order)
    // before lstm_rec2 starts writing H over this region.
    u16* y1bf = (u16*)d_out;
    u16* Xbf  = (u16*)((char*)d_out + 33554432);

    // ---- workspace layout (~155 MB) ----
    char* ws = (char*)d_ws;
    size_t off = 0;
    auto alloc = [&](size_t bytes) { char* p = ws + off; off = (off + bytes + 255) & ~(size_t)255; return p; };
    u16*  Wt1f  = (u16*)alloc(2048ull * 512 * 2);
    u16*  Wt1b  = (u16*)alloc(2048ull * 512 * 2);
    u16*  Wt2f  = (u16*)alloc(2048ull * 1024 * 2);
    u16*  Wt2b  = (u16*)alloc(2048ull * 1024 * 2);
    u16*  Ut1f  = (u16*)alloc(2048ull * 512 * 2);
    u16*  Ut1b  = (u16*)alloc(2048ull * 512 * 2);
    u16*  Ut2f  = (u16*)alloc(2048ull * 512 * 2);
    u16*  Ut2b  = (u16*)alloc(2048ull * 512 * 2);
    int*  maskb = (int*)alloc(16384ull * 4);
    _Float16* xzf = (_Float16*)alloc(16384ull * 2048 * 2);
    _Float16* xzb = (_Float16*)alloc(16384ull * 2048 * 2);
    (void)ws_size; (void)in_sizes; (void)n_in; (void)out_size;

    // prep
    mask_kernel<<<dim3(16384), dim3(64), 0, stream>>>(X, maskb);
    cast_bf16_kernel<<<dim3(8192), dim3(256), 0, stream>>>(X, Xbf, 16384 * 512);
    transpose_cast_kernel<<<dim3(64, 16), dim3(32, 8), 0, stream>>>(Wf1, Wt1f, 512, 2048);
    transpose_cast_kernel<<<dim3(64, 16), dim3(32, 8), 0, stream>>>(Wb1, Wt1b, 512, 2048);
    transpose_cast_kernel<<<dim3(64, 32), dim3(32, 8), 0, stream>>>(Wf2, Wt2f, 1024, 2048);
    transpose_cast_kernel<<<dim3(64, 32), dim3(32, 8), 0, stream>>>(Wb2, Wt2b, 1024, 2048);
    transpose_cast_kernel<<<dim3(64, 16), dim3(32, 8), 0, stream>>>(Uf1, Ut1f, 512, 2048);
    transpose_cast_kernel<<<dim3(64, 16), dim3(32, 8), 0, stream>>>(Ub1, Ut1b, 512, 2048);
    transpose_cast_kernel<<<dim3(64, 16), dim3(32, 8), 0, stream>>>(Uf2, Ut2f, 512, 2048);
    transpose_cast_kernel<<<dim3(64, 16), dim3(32, 8), 0, stream>>>(Ub2, Ut2b, 512, 2048);

    // layer 1
    gemm_xz_kernel<<<dim3(256, 32), dim3(256), 0, stream>>>(Xbf, Wt1f, bf1, xzf, 512);
    gemm_xz_kernel<<<dim3(256, 32), dim3(256), 0, stream>>>(Xbf, Wt1b, bb1, xzb, 512);
    lstm_rec_kernel<<<dim3(4, 2), dim3(1024), 0, stream>>>(
        xzf, xzb, Ut1f, Ut1b, maskb, y1bf, nullptr, nullptr);

    // layer 2
    gemm_xz_kernel<<<dim3(256, 32), dim3(256), 0, stream>>>(y1bf, Wt2f, bf2, xzf, 1024);
    gemm_xz_kernel<<<dim3(256, 32), dim3(256), 0, stream>>>(y1bf, Wt2b, bb2, xzb, 1024);
    lstm_rec_kernel<<<dim3(4, 2), dim3(1024), 0, stream>>>(
        xzf, xzb, Ut2f, Ut2b, maskb, nullptr, out, out + 16777216);
}

// Round 3
// 13968.361 us; speedup vs baseline: 2.3371x; 2.3371x over previous
//
#include <hip/hip_runtime.h>

typedef unsigned short u16;
typedef unsigned int u32;
typedef __attribute__((ext_vector_type(8))) short bf16x8;
typedef __attribute__((ext_vector_type(4))) float f32x4;

#define MFMA16(a, b, c) __builtin_amdgcn_mfma_f32_16x16x32_bf16((a), (b), (c), 0, 0, 0)

__device__ __forceinline__ u16 f2bf(float f) {
    union { float f; u32 u; } v; v.f = f;
    u32 r = v.u + 0x7FFFu + ((v.u >> 16) & 1u);
    return (u16)(r >> 16);
}
__device__ __forceinline__ float sigmoidf_(float x) {
    return 1.0f / (1.0f + __expf(-x));
}
__device__ __forceinline__ float tanhf_(float x) {
    float e = __expf(-2.0f * x);
    return (1.0f - e) / (1.0f + e);
}

// ---------------- mask: mask[row] = any(X[row, :512] != 0) ----------------
__global__ void mask_kernel(const float* __restrict__ X, int* __restrict__ mask) {
    int row = blockIdx.x;
    int lane = threadIdx.x;
    const float* r = X + (size_t)row * 512;
    int nz = 0;
    #pragma unroll
    for (int i = 0; i < 8; ++i) nz |= (r[lane + 64 * i] != 0.0f);
    nz = __any(nz);
    if (lane == 0) mask[row] = nz ? 1 : 0;
}

// ---------------- cast fp32 -> bf16 (4 elems/thread) ----------------
__global__ void cast_bf16_kernel(const float* __restrict__ in, u16* __restrict__ out, int n) {
    int i = (blockIdx.x * blockDim.x + threadIdx.x) * 4;
    if (i + 3 < n) {
        float4 v = *(const float4*)(in + i);
        u32 a = (u32)f2bf(v.x) | ((u32)f2bf(v.y) << 16);
        u32 b = (u32)f2bf(v.z) | ((u32)f2bf(v.w) << 16);
        *(uint2*)(out + i) = make_uint2(a, b);
    }
}

// ---------------- transpose + cast: in fp32 [K][N] -> out bf16 [N][K] ----------------
__global__ void transpose_cast_kernel(const float* __restrict__ in, u16* __restrict__ out,
                                      int K, int N) {
    __shared__ float tile[32][33];
    int k0 = blockIdx.y * 32, n0 = blockIdx.x * 32;
    int tx = threadIdx.x, ty = threadIdx.y;
    #pragma unroll
    for (int i = ty; i < 32; i += 8)
        tile[i][tx] = in[(size_t)(k0 + i) * N + (n0 + tx)];
    __syncthreads();
    #pragma unroll
    for (int i = ty; i < 32; i += 8)
        out[(size_t)(n0 + i) * K + (k0 + tx)] = f2bf(tile[tx][i]);
}

// ---------------- GEMM: C[M][2048] = A[M][K](bf16) @ Bt[N][K](bf16)^T + bias (fp16 out) ----
__global__ __launch_bounds__(256) void gemm_xz_kernel(
        const u16* __restrict__ A, const u16* __restrict__ Bt,
        const float* __restrict__ bias, _Float16* __restrict__ C, int K) {
    const int N = 2048;
    int w = threadIdx.x >> 6, lane = threadIdx.x & 63;
    int q = lane >> 4, col = lane & 15;
    int m0 = blockIdx.x * 64 + w * 16;
    int n0 = blockIdx.y * 64;

    const u16* arow = A + (size_t)(m0 + col) * K + q * 8;
    f32x4 acc[4];
    #pragma unroll
    for (int nt = 0; nt < 4; ++nt) acc[nt] = (f32x4){0.f, 0.f, 0.f, 0.f};

    for (int kc = 0; kc < K; kc += 32) {
        bf16x8 a = *(const bf16x8*)(arow + kc);
        #pragma unroll
        for (int nt = 0; nt < 4; ++nt) {
            bf16x8 b = *(const bf16x8*)(Bt + (size_t)(n0 + nt * 16 + col) * K + kc + q * 8);
            acc[nt] = MFMA16(a, b, acc[nt]);
        }
    }
    int row = m0 + q * 4;
    #pragma unroll
    for (int nt = 0; nt < 4; ++nt) {
        int c_ = n0 + nt * 16 + col;
        float bs = bias[c_];
        #pragma unroll
        for (int r = 0; r < 4; ++r)
            C[(size_t)(row + r) * N + c_] = (_Float16)(acc[nt][r] + bs);
    }
}

// ---------------- zero-init for barrier words + h exchange buffers ----------------
__global__ void init_rec_kernel(u32* __restrict__ p, int n) {
    int i = blockIdx.x * 256 + threadIdx.x;
    if (i < n) p[i] = 0;
}

// ---------------- sense-reversing grid barrier over 32 blocks (agent scope) ----------
__device__ __forceinline__ void grid_barrier32(u32* cnt, u32* gen) {
    __threadfence();          // release: push this block's h stores device-visible
    __syncthreads();
    if (threadIdx.x == 0) {
        u32 g = __hip_atomic_load(gen, __ATOMIC_RELAXED, __HIP_MEMORY_SCOPE_AGENT);
        u32 a = __hip_atomic_fetch_add(cnt, 1u, __ATOMIC_ACQ_REL, __HIP_MEMORY_SCOPE_AGENT);
        if (a == 31u) {
            __hip_atomic_store(cnt, 0u, __ATOMIC_RELAXED, __HIP_MEMORY_SCOPE_AGENT);
            __hip_atomic_fetch_add(gen, 1u, __ATOMIC_RELEASE, __HIP_MEMORY_SCOPE_AGENT);
        } else {
            while (__hip_atomic_load(gen, __ATOMIC_ACQUIRE, __HIP_MEMORY_SCOPE_AGENT) == g)
                __builtin_amdgcn_s_sleep(1);
        }
    }
    __syncthreads();
    __threadfence();          // acquire side: invalidate stale caches before h reads
}

// ---------------- persistent d-sliced LSTM recurrence ----------------
// grid (32 slices, 2 dirs) x 256 thr (4 waves). Block owns 16 h-dims x 4 gates.
// U-slice (64 KB) lives in VGPRs (4 gates x 16 kc x bf16x8). M=64 = whole batch;
// wave w = batch rows [16w,16w+16). Per step: 16 a-frag loads of global h[64][512],
// 64 MFMAs, wave-local gates, h-slice store, grid barrier. No LDS.
__global__ __launch_bounds__(256, 1) void lstm_rec2_kernel(
        const _Float16* __restrict__ xz_f, const _Float16* __restrict__ xz_b,
        const u16* __restrict__ Ut_f, const u16* __restrict__ Ut_b,
        const int* __restrict__ mask,
        u32* __restrict__ bar,      // [dir*32]=cnt, [dir*32+16]=gen
        u16* __restrict__ hg,       // [p][dir][64][512] bf16, p stride 65536
        u16* __restrict__ y_bf,     // layer1 out (null for layer2)
        float* __restrict__ y_f32,  // layer2 H out (null for layer1)
        float* __restrict__ hc_out) // layer2 hidden @0, cell @65536 (null for layer1)
{
    const int T = 256;
    int slice = blockIdx.x, dir = blockIdx.y;
    int tid = threadIdx.x;
    int w = tid >> 6, lane = tid & 63, q = lane >> 4, col = lane & 15;
    int ds = slice * 16, m0 = w * 16;

    const _Float16* xz = dir ? xz_b : xz_f;
    const u16* Ut = dir ? Ut_b : Ut_f;
    u32* cnt = bar + dir * 32;
    u32* gen = bar + dir * 32 + 16;

    // U-slice -> registers: 4 gates x 16 k-chunks, 16 B/lane each (256 VGPRs)
    bf16x8 bfr[4][16];
    #pragma unroll
    for (int g = 0; g < 4; ++g)
        #pragma unroll
        for (int c = 0; c < 16; ++c)
            bfr[g][c] = *(const bf16x8*)(Ut + (size_t)(g * 512 + ds + col) * 512 + c * 32 + q * 8);

    float creg[4] = {0.f, 0.f, 0.f, 0.f};
    float hreg[4] = {0.f, 0.f, 0.f, 0.f};

    for (int it = 0; it < T; ++it) {
        int t = dir ? (T - 1 - it) : it;
        const u16* hsrc = hg + (it & 1) * 65536 + dir * 32768;
        u16* hdst = hg + ((it & 1) ^ 1) * 65536 + dir * 32768;

        // a-fragments of h(t-1): wave's 16 batch rows, all 512 dims
        bf16x8 afr[16];
        #pragma unroll
        for (int c = 0; c < 16; ++c)
            afr[c] = *(const bf16x8*)(hsrc + (size_t)(m0 + col) * 512 + c * 32 + q * 8);

        f32x4 acc[4];
        #pragma unroll
        for (int g = 0; g < 4; ++g) acc[g] = (f32x4){0.f, 0.f, 0.f, 0.f};
        #pragma unroll
        for (int c = 0; c < 16; ++c) {
            #pragma unroll
            for (int g = 0; g < 4; ++g)
                acc[g] = MFMA16(afr[c], bfr[g][c], acc[g]);
        }

        #pragma unroll
        for (int r = 0; r < 4; ++r) {
            int b = m0 + q * 4 + r;
            size_t zrow = ((size_t)b * T + t) * 2048 + ds + col;
            float zi = acc[0][r] + (float)xz[zrow];
            float zf = acc[1][r] + (float)xz[zrow + 512];
            float zg = acc[2][r] + (float)xz[zrow + 1024];
            float zo = acc[3][r] + (float)xz[zrow + 1536];
            float ig = sigmoidf_(zi);
            float fg = sigmoidf_(zf);
            float gg = tanhf_(zg);
            float og = sigmoidf_(zo);
            float cn = fg * creg[r] + ig * gg;
            float hn = og * tanhf_(cn);
            if (mask[b * T + t]) { creg[r] = cn; hreg[r] = hn; }
            u16 hb = f2bf(hreg[r]);
            hdst[(size_t)b * 512 + ds + col] = hb;
            size_t ybase = ((size_t)b * T + t) * 1024 + dir * 512 + ds + col;
            if (y_bf) y_bf[ybase] = hb;
            else      y_f32[ybase] = hreg[r];
        }

        grid_barrier32(cnt, gen);
    }

    if (hc_out) {
        #pragma unroll
        for (int r = 0; r < 4; ++r) {
            int b = m0 + q * 4 + r;
            hc_out[(size_t)b * 1024 + dir * 512 + ds + col] = hreg[r];
            hc_out[65536 + (size_t)b * 1024 + dir * 512 + ds + col] = creg[r];
        }
    }
}

extern "C" void kernel_launch(void* const* d_in, const int* in_sizes, int n_in,
                              void* d_out, int out_size, void* d_ws, size_t ws_size,
                              hipStream_t stream) {
    const float* X   = (const float*)d_in[0];
    const float* Wf1 = (const float*)d_in[1];
    const float* Uf1 = (const float*)d_in[2];
    const float* bf1 = (const float*)d_in[3];
    const float* Wb1 = (const float*)d_in[4];
    const float* Ub1 = (const float*)d_in[5];
    const float* bb1 = (const float*)d_in[6];
    const float* Wf2 = (const float*)d_in[7];
    const float* Uf2 = (const float*)d_in[8];
    const float* bf2 = (const float*)d_in[9];
    const float* Wb2 = (const float*)d_in[10];
    const float* Ub2 = (const float*)d_in[11];
    const float* bb2 = (const float*)d_in[12];
    float* out = (float*)d_out;

    // scratch carved from d_out's H region (67.1 MB, dead until lstm_rec2 layer-2):
    // y1bf 33.55 MB @0, Xbf 16.78 MB after; both consumed by layer-2 GEMMs (stream order).
    u16* y1bf = (u16*)d_out;
    u16* Xbf  = (u16*)((char*)d_out + 33554432);

    char* ws = (char*)d_ws;
    size_t off = 0;
    auto alloc = [&](size_t bytes) { char* p = ws + off; off = (off + bytes + 255) & ~(size_t)255; return p; };
    u16*  Wt1f  = (u16*)alloc(2048ull * 512 * 2);
    u16*  Wt1b  = (u16*)alloc(2048ull * 512 * 2);
    u16*  Wt2f  = (u16*)alloc(2048ull * 1024 * 2);
    u16*  Wt2b  = (u16*)alloc(2048ull * 1024 * 2);
    u16*  Ut1f  = (u16*)alloc(2048ull * 512 * 2);
    u16*  Ut1b  = (u16*)alloc(2048ull * 512 * 2);
    u16*  Ut2f  = (u16*)alloc(2048ull * 512 * 2);
    u16*  Ut2b  = (u16*)alloc(2048ull * 512 * 2);
    int*  maskb = (int*)alloc(16384ull * 4);
    // barrier words (512 B) + h exchange buffers (2 bufs x 2 dirs x 64 x 512 bf16 = 256 KB),
    // contiguous so one init kernel zeroes both.
    u32*  bar   = (u32*)alloc(512);
    u16*  hg    = (u16*)alloc(2ull * 2 * 64 * 512 * 2);
    _Float16* xzf = (_Float16*)alloc(16384ull * 2048 * 2);
    _Float16* xzb = (_Float16*)alloc(16384ull * 2048 * 2);
    (void)ws_size; (void)in_sizes; (void)n_in; (void)out_size;
    const int initN = (512 + 262144) / 4;  // bar + hg in u32s

    // prep
    mask_kernel<<<dim3(16384), dim3(64), 0, stream>>>(X, maskb);
    cast_bf16_kernel<<<dim3(8192), dim3(256), 0, stream>>>(X, Xbf, 16384 * 512);
    transpose_cast_kernel<<<dim3(64, 16), dim3(32, 8), 0, stream>>>(Wf1, Wt1f, 512, 2048);
    transpose_cast_kernel<<<dim3(64, 16), dim3(32, 8), 0, stream>>>(Wb1, Wt1b, 512, 2048);
    transpose_cast_kernel<<<dim3(64, 32), dim3(32, 8), 0, stream>>>(Wf2, Wt2f, 1024, 2048);
    transpose_cast_kernel<<<dim3(64, 32), dim3(32, 8), 0, stream>>>(Wb2, Wt2b, 1024, 2048);
    transpose_cast_kernel<<<dim3(64, 16), dim3(32, 8), 0, stream>>>(Uf1, Ut1f, 512, 2048);
    transpose_cast_kernel<<<dim3(64, 16), dim3(32, 8), 0, stream>>>(Ub1, Ut1b, 512, 2048);
    transpose_cast_kernel<<<dim3(64, 16), dim3(32, 8), 0, stream>>>(Uf2, Ut2f, 512, 2048);
    transpose_cast_kernel<<<dim3(64, 16), dim3(32, 8), 0, stream>>>(Ub2, Ut2b, 512, 2048);

    // layer 1
    gemm_xz_kernel<<<dim3(256, 32), dim3(256), 0, stream>>>(Xbf, Wt1f, bf1, xzf, 512);
    gemm_xz_kernel<<<dim3(256, 32), dim3(256), 0, stream>>>(Xbf, Wt1b, bb1, xzb, 512);
    init_rec_kernel<<<dim3((initN + 255) / 256), dim3(256), 0, stream>>>(bar, initN);
    lstm_rec2_kernel<<<dim3(32, 2), dim3(256), 0, stream>>>(
        xzf, xzb, Ut1f, Ut1b, maskb, bar, hg, y1bf, nullptr, nullptr);

    // layer 2
    gemm_xz_kernel<<<dim3(256, 32), dim3(256), 0, stream>>>(y1bf, Wt2f, bf2, xzf, 1024);
    gemm_xz_kernel<<<dim3(256, 32), dim3(256), 0, stream>>>(y1bf, Wt2b, bb2, xzb, 1024);
    init_rec_kernel<<<dim3((initN + 255) / 256), dim3(256), 0, stream>>>(bar, initN);
    lstm_rec2_kernel<<<dim3(32, 2), dim3(256), 0, stream>>>(
        xzf, xzb, Ut2f, Ut2b, maskb, bar, hg, nullptr, out, out + 16777216);
}

// Round 5
// 6354.366 us; speedup vs baseline: 5.1375x; 2.1982x over previous
//
#include <hip/hip_runtime.h>

typedef unsigned short u16;
typedef unsigned int u32;
typedef __attribute__((ext_vector_type(8))) short bf16x8;
typedef __attribute__((ext_vector_type(4))) float f32x4;
typedef __attribute__((ext_vector_type(4))) _Float16 f16x4;

#define MFMA16(a, b, c) __builtin_amdgcn_mfma_f32_16x16x32_bf16((a), (b), (c), 0, 0, 0)

__device__ __forceinline__ u16 f2bf(float f) {
    union { float f; u32 u; } v; v.f = f;
    u32 r = v.u + 0x7FFFu + ((v.u >> 16) & 1u);
    return (u16)(r >> 16);
}
__device__ __forceinline__ float sigmoidf_(float x) {
    return 1.0f / (1.0f + __expf(-x));
}
__device__ __forceinline__ float tanhf_(float x) {
    float e = __expf(-2.0f * x);
    return (1.0f - e) / (1.0f + e);
}

// ---------------- mask: mask[row] = any(X[row, :512] != 0) ----------------
__global__ void mask_kernel(const float* __restrict__ X, int* __restrict__ mask) {
    int row = blockIdx.x;
    int lane = threadIdx.x;
    const float* r = X + (size_t)row * 512;
    int nz = 0;
    #pragma unroll
    for (int i = 0; i < 8; ++i) nz |= (r[lane + 64 * i] != 0.0f);
    nz = __any(nz);
    if (lane == 0) mask[row] = nz ? 1 : 0;
}

// ---------------- cast fp32 -> bf16 (4 elems/thread) ----------------
__global__ void cast_bf16_kernel(const float* __restrict__ in, u16* __restrict__ out, int n) {
    int i = (blockIdx.x * blockDim.x + threadIdx.x) * 4;
    if (i + 3 < n) {
        float4 v = *(const float4*)(in + i);
        u32 a = (u32)f2bf(v.x) | ((u32)f2bf(v.y) << 16);
        u32 b = (u32)f2bf(v.z) | ((u32)f2bf(v.w) << 16);
        *(uint2*)(out + i) = make_uint2(a, b);
    }
}

// ---------------- transpose + cast: in fp32 [K][N] -> out bf16 [N][K] ----------------
__global__ void transpose_cast_kernel(const float* __restrict__ in, u16* __restrict__ out,
                                      int K, int N) {
    __shared__ float tile[32][33];
    int k0 = blockIdx.y * 32, n0 = blockIdx.x * 32;
    int tx = threadIdx.x, ty = threadIdx.y;
    #pragma unroll
    for (int i = ty; i < 32; i += 8)
        tile[i][tx] = in[(size_t)(k0 + i) * N + (n0 + tx)];
    __syncthreads();
    #pragma unroll
    for (int i = ty; i < 32; i += 8)
        out[(size_t)(n0 + i) * K + (k0 + tx)] = f2bf(tile[tx][i]);
}

// ---------------- GEMM: xz = A @ Bt^T + bias, output in rec-friendly layout ----------
// C element index: (((t*32 + slice)*64 + b)*16 + dcol)*4 + g   (fp16)
// where m-row = b*256+t, n-col = g*512 + slice*16 + dcol.
__global__ __launch_bounds__(256) void gemm_xz_kernel(
        const u16* __restrict__ A, const u16* __restrict__ Bt,
        const float* __restrict__ bias, _Float16* __restrict__ C, int K) {
    int w = threadIdx.x >> 6, lane = threadIdx.x & 63;
    int q = lane >> 4, col = lane & 15;
    int m0 = blockIdx.x * 64 + w * 16;
    int n0 = blockIdx.y * 64;

    const u16* arow = A + (size_t)(m0 + col) * K + q * 8;
    f32x4 acc[4];
    #pragma unroll
    for (int nt = 0; nt < 4; ++nt) acc[nt] = (f32x4){0.f, 0.f, 0.f, 0.f};

    for (int kc = 0; kc < K; kc += 32) {
        bf16x8 a = *(const bf16x8*)(arow + kc);
        #pragma unroll
        for (int nt = 0; nt < 4; ++nt) {
            bf16x8 b = *(const bf16x8*)(Bt + (size_t)(n0 + nt * 16 + col) * K + kc + q * 8);
            acc[nt] = MFMA16(a, b, acc[nt]);
        }
    }
    #pragma unroll
    for (int nt = 0; nt < 4; ++nt) {
        int n = n0 + nt * 16 + col;
        int g = n >> 9, d = n & 511;
        float bs = bias[n];
        #pragma unroll
        for (int r = 0; r < 4; ++r) {
            int row = m0 + q * 4 + r;
            int b = row >> 8, t = row & 255;
            size_t idx = ((((size_t)t * 32 + (d >> 4)) * 64 + b) * 16 + (d & 15)) * 4 + g;
            C[idx] = (_Float16)(acc[nt][r] + bs);
        }
    }
}

// ---------------- zero-init (flags + h exchange buffers) ----------------
__global__ void init_rec_kernel(u32* __restrict__ p, int n) {
    int i = blockIdx.x * 256 + threadIdx.x;
    if (i < n) p[i] = 0;
}

// ---------------- persistent d-sliced LSTM recurrence, v4 ----------------
// grid (32 slices, 2 dirs) x 256 thr (4 waves). Block owns 16 h-dims x 4 gates.
// U-slice (68.6 KB) in LDS. h exchange: normal stores (write-back) + per-(dir,slice)
// flag via thread0 fetch_add(RELEASE, AGENT) after __syncthreads (release = vmcnt
// drain + buffer_wbl2 -> h visible at LLC). Consumers: relaxed agent polls of the
// 32 producer flags, then one agent ACQUIRE fence (buffer_inv) before h loads.
// All primitives behaviorally proven by R3's working barrier. No inline asm.
// Double-buffer safety: flag>=k certifies h^k written, which data-depends on having
// consumed h^{k-1}; overwrite of h^{k-1} happens only after all flags >= k.
__global__ __launch_bounds__(256) void lstm_rec4_kernel(
        const _Float16* __restrict__ xz_f, const _Float16* __restrict__ xz_b,
        const u16* __restrict__ Ut_f, const u16* __restrict__ Ut_b,
        const int* __restrict__ mask,
        u32* __restrict__ flags,    // [dir*32 + slice] monotone step counters
        u16* __restrict__ hg,       // [slot][dir][64][512] bf16, slot stride 65536
        u16* __restrict__ y_bf,     // layer1 out (null for layer2)
        float* __restrict__ y_f32,  // layer2 H out (null for layer1)
        float* __restrict__ hc_out) // layer2 hidden @0, cell @65536 (null for layer1)
{
    const int T = 256;
    int slice = blockIdx.x, dir = blockIdx.y;
    int tid = threadIdx.x;
    int w = tid >> 6, lane = tid & 63, q = lane >> 4, col = lane & 15;
    int ds = slice * 16, m0 = w * 16;

    const _Float16* xz = dir ? xz_b : xz_f;
    const u16* Ut = dir ? Ut_b : Ut_f;
    u32* dirflags = flags + dir * 32;
    u32* myflag = dirflags + slice;

    // ---- stage U-slice into LDS once: Ulds[g][dcol][k], k-stride 536 (16B-mult) ----
    alignas(16) __shared__ u16 Ulds[4][16][536];
    for (int c2 = tid; c2 < 4096; c2 += 256) {
        int rowi = c2 >> 6, chunk = c2 & 63;
        int g = rowi >> 4, cr = rowi & 15;
        *(uint4*)&Ulds[g][cr][chunk * 8] =
            *(const uint4*)(Ut + (size_t)(g * 512 + ds + cr) * 512 + chunk * 8);
    }

    float creg[4] = {0.f, 0.f, 0.f, 0.f};
    float hreg[4] = {0.f, 0.f, 0.f, 0.f};
    __syncthreads();

    for (int it = 0; it < T; ++it) {
        int t = dir ? (T - 1 - it) : it;
        const u16* hsrc = hg + (it & 1) * 65536 + dir * 32768;
        u16* hdst = hg + ((it & 1) ^ 1) * 65536 + dir * 32768;

        // xz + mask loads for this step (independent of h) — issued before the poll
        f16x4 xzv[4];
        {
            const _Float16* xzt = xz + (((size_t)t * 32 + slice) * 64) * 64;
            #pragma unroll
            for (int r = 0; r < 4; ++r)
                xzv[r] = *(const f16x4*)(xzt + ((m0 + q * 4 + r) * 16 + col) * 4);
        }
        int mk[4];
        #pragma unroll
        for (int r = 0; r < 4; ++r) mk[r] = mask[(m0 + q * 4 + r) * T + t];

        // ---- wait for all 32 producer blocks of this dir to publish h^{it} ----
        if (it) {
            u32 tgt = (u32)it;
            for (;;) {
                u32 f = __hip_atomic_load(dirflags + (lane & 31), __ATOMIC_RELAXED,
                                          __HIP_MEMORY_SCOPE_AGENT);
                if (__all(f >= tgt)) break;
                __builtin_amdgcn_s_sleep(1);
            }
            __builtin_amdgcn_fence(__ATOMIC_ACQUIRE, "agent");  // buffer_inv
        }

        // ---- a-fragments of h^{it}: wave's 16 batch rows, all 512 dims ----
        bf16x8 afr[16];
        {
            const u16* hp = hsrc + (size_t)(m0 + col) * 512 + q * 8;
            #pragma unroll
            for (int c = 0; c < 16; ++c)
                afr[c] = *(const bf16x8*)(hp + c * 32);
        }

        // ---- z = h @ U for 4 gates x 16 dims x wave's 16 rows ----
        f32x4 acc[4];
        #pragma unroll
        for (int g = 0; g < 4; ++g) acc[g] = (f32x4){0.f, 0.f, 0.f, 0.f};
        #pragma unroll
        for (int kc = 0; kc < 16; ++kc) {
            #pragma unroll
            for (int g = 0; g < 4; ++g) {
                bf16x8 b = *(const bf16x8*)&Ulds[g][col][kc * 32 + q * 8];
                acc[g] = MFMA16(afr[kc], b, acc[g]);
            }
        }

        // ---- gates, state update, h + y stores ----
        #pragma unroll
        for (int r = 0; r < 4; ++r) {
            int b = m0 + q * 4 + r;
            float zi = acc[0][r] + (float)xzv[r][0];
            float zf = acc[1][r] + (float)xzv[r][1];
            float zg = acc[2][r] + (float)xzv[r][2];
            float zo = acc[3][r] + (float)xzv[r][3];
            float ig = sigmoidf_(zi);
            float fg = sigmoidf_(zf);
            float gg = tanhf_(zg);
            float og = sigmoidf_(zo);
            float cn = fg * creg[r] + ig * gg;
            float hn = og * tanhf_(cn);
            if (mk[r]) { creg[r] = cn; hreg[r] = hn; }
            u16 hb = f2bf(hreg[r]);
            hdst[(size_t)b * 512 + ds + col] = hb;  // write-back; flushed by release below
            size_t ybase = ((size_t)b * T + t) * 1024 + dir * 512 + ds + col;
            if (y_bf) __builtin_nontemporal_store(hb, y_bf + ybase);
            else      __builtin_nontemporal_store(hreg[r], y_f32 + ybase);
        }

        // ---- publish: all waves' stores at L2, then release-RMW (wbl2 + add) ----
        __syncthreads();
        if (tid == 0)
            __hip_atomic_fetch_add(myflag, 1u, __ATOMIC_RELEASE, __HIP_MEMORY_SCOPE_AGENT);
    }

    if (hc_out) {
        #pragma unroll
        for (int r = 0; r < 4; ++r) {
            int b = m0 + q * 4 + r;
            hc_out[(size_t)b * 1024 + dir * 512 + ds + col] = hreg[r];
            hc_out[65536 + (size_t)b * 1024 + dir * 512 + ds + col] = creg[r];
        }
    }
}

extern "C" void kernel_launch(void* const* d_in, const int* in_sizes, int n_in,
                              void* d_out, int out_size, void* d_ws, size_t ws_size,
                              hipStream_t stream) {
    const float* X   = (const float*)d_in[0];
    const float* Wf1 = (const float*)d_in[1];
    const float* Uf1 = (const float*)d_in[2];
    const float* bf1 = (const float*)d_in[3];
    const float* Wb1 = (const float*)d_in[4];
    const float* Ub1 = (const float*)d_in[5];
    const float* bb1 = (const float*)d_in[6];
    const float* Wf2 = (const float*)d_in[7];
    const float* Uf2 = (const float*)d_in[8];
    const float* bf2 = (const float*)d_in[9];
    const float* Wb2 = (const float*)d_in[10];
    const float* Ub2 = (const float*)d_in[11];
    const float* bb2 = (const float*)d_in[12];
    float* out = (float*)d_out;

    // scratch carved from d_out's H region (67.1 MB, dead until layer-2 rec):
    // y1bf 33.55 MB @0, Xbf 16.78 MB after; both consumed by layer-2 GEMMs (stream order).
    u16* y1bf = (u16*)d_out;
    u16* Xbf  = (u16*)((char*)d_out + 33554432);

    char* ws = (char*)d_ws;
    size_t off = 0;
    auto alloc = [&](size_t bytes) { char* p = ws + off; off = (off + bytes + 255) & ~(size_t)255; return p; };
    u16*  Wt1f  = (u16*)alloc(2048ull * 512 * 2);
    u16*  Wt1b  = (u16*)alloc(2048ull * 512 * 2);
    u16*  Wt2f  = (u16*)alloc(2048ull * 1024 * 2);
    u16*  Wt2b  = (u16*)alloc(2048ull * 1024 * 2);
    u16*  Ut1f  = (u16*)alloc(2048ull * 512 * 2);
    u16*  Ut1b  = (u16*)alloc(2048ull * 512 * 2);
    u16*  Ut2f  = (u16*)alloc(2048ull * 512 * 2);
    u16*  Ut2b  = (u16*)alloc(2048ull * 512 * 2);
    int*  maskb = (int*)alloc(16384ull * 4);
    // flags (64 u32, padded to 1 KB) + h exchange (2 slots x 2 dirs x 64 x 512 bf16 =
    // 256 KB), contiguous so one init kernel zeroes both.
    u32*  flags = (u32*)alloc(1024);
    u16*  hg    = (u16*)alloc(2ull * 2 * 64 * 512 * 2);
    _Float16* xzf = (_Float16*)alloc(16384ull * 2048 * 2);
    _Float16* xzb = (_Float16*)alloc(16384ull * 2048 * 2);
    (void)ws_size; (void)in_sizes; (void)n_in; (void)out_size;
    const int initN = (1024 + 262144) / 4;

    // prep
    mask_kernel<<<dim3(16384), dim3(64), 0, stream>>>(X, maskb);
    cast_bf16_kernel<<<dim3(8192), dim3(256), 0, stream>>>(X, Xbf, 16384 * 512);
    transpose_cast_kernel<<<dim3(64, 16), dim3(32, 8), 0, stream>>>(Wf1, Wt1f, 512, 2048);
    transpose_cast_kernel<<<dim3(64, 16), dim3(32, 8), 0, stream>>>(Wb1, Wt1b, 512, 2048);
    transpose_cast_kernel<<<dim3(64, 32), dim3(32, 8), 0, stream>>>(Wf2, Wt2f, 1024, 2048);
    transpose_cast_kernel<<<dim3(64, 32), dim3(32, 8), 0, stream>>>(Wb2, Wt2b, 1024, 2048);
    transpose_cast_kernel<<<dim3(64, 16), dim3(32, 8), 0, stream>>>(Uf1, Ut1f, 512, 2048);
    transpose_cast_kernel<<<dim3(64, 16), dim3(32, 8), 0, stream>>>(Ub1, Ut1b, 512, 2048);
    transpose_cast_kernel<<<dim3(64, 16), dim3(32, 8), 0, stream>>>(Uf2, Ut2f, 512, 2048);
    transpose_cast_kernel<<<dim3(64, 16), dim3(32, 8), 0, stream>>>(Ub2, Ut2b, 512, 2048);

    // layer 1
    gemm_xz_kernel<<<dim3(256, 32), dim3(256), 0, stream>>>(Xbf, Wt1f, bf1, xzf, 512);
    gemm_xz_kernel<<<dim3(256, 32), dim3(256), 0, stream>>>(Xbf, Wt1b, bb1, xzb, 512);
    init_rec_kernel<<<dim3((initN + 255) / 256), dim3(256), 0, stream>>>(flags, initN);
    lstm_rec4_kernel<<<dim3(32, 2), dim3(256), 0, stream>>>(
        xzf, xzb, Ut1f, Ut1b, maskb, flags, hg, y1bf, nullptr, nullptr);

    // layer 2
    gemm_xz_kernel<<<dim3(256, 32), dim3(256), 0, stream>>>(y1bf, Wt2f, bf2, xzf, 1024);
    gemm_xz_kernel<<<dim3(256, 32), dim3(256), 0, stream>>>(y1bf, Wt2b, bb2, xzb, 1024);
    init_rec_kernel<<<dim3((initN + 255) / 256), dim3(256), 0, stream>>>(flags, initN);
    lstm_rec4_kernel<<<dim3(32, 2), dim3(256), 0, stream>>>(
        xzf, xzb, Ut2f, Ut2b, maskb, flags, hg, nullptr, out, out + 16777216);
}

// Round 8
// 5861.185 us; speedup vs baseline: 5.5697x; 1.0841x over previous
//
#include <hip/hip_runtime.h>

typedef unsigned short u16;
typedef unsigned int u32;
typedef unsigned long long u64;
typedef __attribute__((ext_vector_type(8))) short bf16x8;
typedef __attribute__((ext_vector_type(4))) float f32x4;
typedef __attribute__((ext_vector_type(4))) _Float16 f16x4;

#define MFMA16(a, b, c) __builtin_amdgcn_mfma_f32_16x16x32_bf16((a), (b), (c), 0, 0, 0)

__device__ __forceinline__ u16 f2bf(float f) {
    union { float f; u32 u; } v; v.f = f;
    u32 r = v.u + 0x7FFFu + ((v.u >> 16) & 1u);
    return (u16)(r >> 16);
}
__device__ __forceinline__ float sigmoidf_(float x) {
    return 1.0f / (1.0f + __expf(-x));
}
__device__ __forceinline__ float tanhf_(float x) {
    float e = __expf(-2.0f * x);
    return (1.0f - e) / (1.0f + e);
}

// ---------------- mask: mask[row] = any(X[row, :512] != 0) ----------------
__global__ void mask_kernel(const float* __restrict__ X, int* __restrict__ mask) {
    int row = blockIdx.x;
    int lane = threadIdx.x;
    const float* r = X + (size_t)row * 512;
    int nz = 0;
    #pragma unroll
    for (int i = 0; i < 8; ++i) nz |= (r[lane + 64 * i] != 0.0f);
    nz = __any(nz);
    if (lane == 0) mask[row] = nz ? 1 : 0;
}

// ---------------- cast fp32 -> bf16 (4 elems/thread) ----------------
__global__ void cast_bf16_kernel(const float* __restrict__ in, u16* __restrict__ out, int n) {
    int i = (blockIdx.x * blockDim.x + threadIdx.x) * 4;
    if (i + 3 < n) {
        float4 v = *(const float4*)(in + i);
        u32 a = (u32)f2bf(v.x) | ((u32)f2bf(v.y) << 16);
        u32 b = (u32)f2bf(v.z) | ((u32)f2bf(v.w) << 16);
        *(uint2*)(out + i) = make_uint2(a, b);
    }
}

// ---------------- transpose + cast: in fp32 [K][N] -> out bf16 [N][K] ----------------
__global__ void transpose_cast_kernel(const float* __restrict__ in, u16* __restrict__ out,
                                      int K, int N) {
    __shared__ float tile[32][33];
    int k0 = blockIdx.y * 32, n0 = blockIdx.x * 32;
    int tx = threadIdx.x, ty = threadIdx.y;
    #pragma unroll
    for (int i = ty; i < 32; i += 8)
        tile[i][tx] = in[(size_t)(k0 + i) * N + (n0 + tx)];
    __syncthreads();
    #pragma unroll
    for (int i = ty; i < 32; i += 8)
        out[(size_t)(n0 + i) * K + (k0 + tx)] = f2bf(tile[tx][i]);
}

// ---------------- GEMM: xz = A @ Bt^T + bias, output in rec-friendly layout ----------
// C element index: (((t*32 + slice)*64 + b)*16 + dcol)*4 + g   (fp16)
// where m-row = b*256+t, n-col = g*512 + slice*16 + dcol.
__global__ __launch_bounds__(256) void gemm_xz_kernel(
        const u16* __restrict__ A, const u16* __restrict__ Bt,
        const float* __restrict__ bias, _Float16* __restrict__ C, int K) {
    int w = threadIdx.x >> 6, lane = threadIdx.x & 63;
    int q = lane >> 4, col = lane & 15;
    int m0 = blockIdx.x * 64 + w * 16;
    int n0 = blockIdx.y * 64;

    const u16* arow = A + (size_t)(m0 + col) * K + q * 8;
    f32x4 acc[4];
    #pragma unroll
    for (int nt = 0; nt < 4; ++nt) acc[nt] = (f32x4){0.f, 0.f, 0.f, 0.f};

    for (int kc = 0; kc < K; kc += 32) {
        bf16x8 a = *(const bf16x8*)(arow + kc);
        #pragma unroll
        for (int nt = 0; nt < 4; ++nt) {
            bf16x8 b = *(const bf16x8*)(Bt + (size_t)(n0 + nt * 16 + col) * K + kc + q * 8);
            acc[nt] = MFMA16(a, b, acc[nt]);
        }
    }
    #pragma unroll
    for (int nt = 0; nt < 4; ++nt) {
        int n = n0 + nt * 16 + col;
        int g = n >> 9, d = n & 511;
        float bs = bias[n];
        #pragma unroll
        for (int r = 0; r < 4; ++r) {
            int row = m0 + q * 4 + r;
            int b = row >> 8, t = row & 255;
            size_t idx = ((((size_t)t * 32 + (d >> 4)) * 64 + b) * 16 + (d & 15)) * 4 + g;
            C[idx] = (_Float16)(acc[nt][r] + bs);
        }
    }
}

// ---------------- zero-init (flags + h exchange buffers) ----------------
__global__ void init_rec_kernel(u32* __restrict__ p, int n) {
    int i = blockIdx.x * 256 + threadIdx.x;
    if (i < n) p[i] = 0;
}

// ---------------- persistent d-sliced LSTM recurrence, v7 ----------------
// grid (32 slices, 2 dirs) x 256 thr (4 waves). Block owns 16 h-dims x 4 gates.
// U-slice in LDS, per-fragment contiguous (lane l reads 16 B at base+16l ->
// 8 accesses/bank = conflict-free minimum).
// Publish (R5-proven): plain u16 h stores -> __syncthreads (vmcnt drain) -> thread0
//   fetch_add(RELEASE, AGENT) = buffer_wbl2 (producer L2 -> LLC) + flag RMW at LLC.
// Consume: relaxed AGENT polls of 32 flags, then relaxed AGENT u64 atomic loads of
//   h (LLC-coherent; R6/R7's bit-identical failures prove both protocols delivered
//   FRESH data — the bug was a u64 stride error, fixed below: chunk stride is
//   32 u16 = 8 u64, not 4).
// Double-buffer safety: flag>=k certifies h^k written (data-dep on consuming
// h^{k-1}); slot overwrite only after all flags >= k. Max skew 1 step, 2 slots.
__global__ __launch_bounds__(256) void lstm_rec7_kernel(
        const _Float16* __restrict__ xz_f, const _Float16* __restrict__ xz_b,
        const u16* __restrict__ Ut_f, const u16* __restrict__ Ut_b,
        const int* __restrict__ mask,
        u32* __restrict__ flags,    // [dir*32 + slice] monotone step counters
        u16* __restrict__ hg,       // [slot][dir][64][512] bf16, slot stride 65536
        u16* __restrict__ y_bf,     // layer1 out (null for layer2)
        float* __restrict__ y_f32,  // layer2 H out (null for layer1)
        float* __restrict__ hc_out) // layer2 hidden @0, cell @65536 (null for layer1)
{
    const int T = 256;
    int slice = blockIdx.x, dir = blockIdx.y;
    int tid = threadIdx.x;
    int lane = tid & 63, q = lane >> 4, col = lane & 15;
    int ds = slice * 16, m0 = (tid >> 6) * 16;

    const _Float16* xz = dir ? xz_b : xz_f;
    const u16* Ut = dir ? Ut_b : Ut_f;
    u32* dirflags = flags + dir * 32;
    u32* myflag = dirflags + slice;

    // ---- stage U-slice into LDS once, per-fragment contiguous ----
    // cell = (g*16+kc)*64 + l; holds U[g*512+ds+(l&15)][kc*32+(l>>4)*8 ..+8].
    alignas(16) __shared__ u16 Ulds[4 * 16 * 64 * 8];  // 64 KB
    for (int cell = tid; cell < 4096; cell += 256) {
        int l = cell & 63, fr = cell >> 6;
        int kc = fr & 15, g = fr >> 4;
        *(uint4*)&Ulds[cell * 8] =
            *(const uint4*)(Ut + (size_t)(g * 512 + ds + (l & 15)) * 512 + kc * 32 + (l >> 4) * 8);
    }

    float creg[4] = {0.f, 0.f, 0.f, 0.f};
    float hreg[4] = {0.f, 0.f, 0.f, 0.f};
    __syncthreads();

    for (int it = 0; it < T; ++it) {
        int t = dir ? (T - 1 - it) : it;
        const u16* hsrc = hg + (it & 1) * 65536 + dir * 32768;
        u16* hdst = hg + ((it & 1) ^ 1) * 65536 + dir * 32768;

        // xz + mask loads for this step (independent of h) — issued before the poll
        f16x4 xzv[4];
        {
            const _Float16* xzt = xz + (((size_t)t * 32 + slice) * 64) * 64;
            #pragma unroll
            for (int r = 0; r < 4; ++r)
                xzv[r] = *(const f16x4*)(xzt + ((m0 + q * 4 + r) * 16 + col) * 4);
        }
        int mk[4];
        #pragma unroll
        for (int r = 0; r < 4; ++r) mk[r] = mask[(m0 + q * 4 + r) * T + t];

        // ---- wait for all 32 producer blocks of this dir to publish h^{it} ----
        if (it) {
            u32 tgt = (u32)it;
            for (;;) {
                u32 f = __hip_atomic_load(dirflags + (lane & 31), __ATOMIC_RELAXED,
                                          __HIP_MEMORY_SCOPE_AGENT);
                if (__all(f >= tgt)) break;
                __builtin_amdgcn_s_sleep(1);
            }
            __builtin_amdgcn_sched_barrier(0);  // pin h loads after the poll
        }

        // ---- a-fragments of h^{it} via relaxed agent u64 loads (LLC-coherent) ----
        // chunk c covers k = c*32 + q*8 .. +8  (32 u16 = 8 u64 stride — R6/R7 bug was c*4)
        bf16x8 afr[16];
        {
            const u64* hp = (const u64*)(hsrc + (size_t)(m0 + col) * 512 + q * 8);
            #pragma unroll
            for (int c = 0; c < 16; ++c) {
                union { u64 qw[2]; bf16x8 v; } u;
                u.qw[0] = __hip_atomic_load(hp + c * 8, __ATOMIC_RELAXED,
                                            __HIP_MEMORY_SCOPE_AGENT);
                u.qw[1] = __hip_atomic_load(hp + c * 8 + 1, __ATOMIC_RELAXED,
                                            __HIP_MEMORY_SCOPE_AGENT);
                afr[c] = u.v;
            }
        }

        // ---- z = h @ U for 4 gates x 16 dims x wave's 16 rows ----
        f32x4 acc[4];
        #pragma unroll
        for (int g = 0; g < 4; ++g) acc[g] = (f32x4){0.f, 0.f, 0.f, 0.f};
        #pragma unroll
        for (int kc = 0; kc < 16; ++kc) {
            #pragma unroll
            for (int g = 0; g < 4; ++g) {
                bf16x8 b = *(const bf16x8*)&Ulds[((g * 16 + kc) * 64 + lane) * 8];
                acc[g] = MFMA16(afr[kc], b, acc[g]);
            }
        }

        // ---- gates, state update, h (plain stores) + y stores ----
        #pragma unroll
        for (int r = 0; r < 4; ++r) {
            int b = m0 + q * 4 + r;
            float zi = acc[0][r] + (float)xzv[r][0];
            float zf = acc[1][r] + (float)xzv[r][1];
            float zg = acc[2][r] + (float)xzv[r][2];
            float zo = acc[3][r] + (float)xzv[r][3];
            float ig = sigmoidf_(zi);
            float fg = sigmoidf_(zf);
            float gg = tanhf_(zg);
            float og = sigmoidf_(zo);
            float cn = fg * creg[r] + ig * gg;
            float hn = og * tanhf_(cn);
            if (mk[r]) { creg[r] = cn; hreg[r] = hn; }
            u16 hb = f2bf(hreg[r]);
            hdst[(size_t)b * 512 + ds + col] = hb;  // write-back; flushed by release RMW
            size_t ybase = ((size_t)b * T + t) * 1024 + dir * 512 + ds + col;
            if (y_bf) __builtin_nontemporal_store(hb, y_bf + ybase);
            else      __builtin_nontemporal_store(hreg[r], y_f32 + ybase);
        }

        // ---- publish: all waves drained at L2 (syncthreads), then release RMW ----
        __syncthreads();
        if (tid == 0)
            __hip_atomic_fetch_add(myflag, 1u, __ATOMIC_RELEASE, __HIP_MEMORY_SCOPE_AGENT);
    }

    if (hc_out) {
        #pragma unroll
        for (int r = 0; r < 4; ++r) {
            int b = m0 + q * 4 + r;
            hc_out[(size_t)b * 1024 + dir * 512 + ds + col] = hreg[r];
            hc_out[65536 + (size_t)b * 1024 + dir * 512 + ds + col] = creg[r];
        }
    }
}

extern "C" void kernel_launch(void* const* d_in, const int* in_sizes, int n_in,
                              void* d_out, int out_size, void* d_ws, size_t ws_size,
                              hipStream_t stream) {
    const float* X   = (const float*)d_in[0];
    const float* Wf1 = (const float*)d_in[1];
    const float* Uf1 = (const float*)d_in[2];
    const float* bf1 = (const float*)d_in[3];
    const float* Wb1 = (const float*)d_in[4];
    const float* Ub1 = (const float*)d_in[5];
    const float* bb1 = (const float*)d_in[6];
    const float* Wf2 = (const float*)d_in[7];
    const float* Uf2 = (const float*)d_in[8];
    const float* bf2 = (const float*)d_in[9];
    const float* Wb2 = (const float*)d_in[10];
    const float* Ub2 = (const float*)d_in[11];
    const float* bb2 = (const float*)d_in[12];
    float* out = (float*)d_out;

    // scratch carved from d_out's H region (67.1 MB, dead until layer-2 rec):
    // y1bf 33.55 MB @0, Xbf 16.78 MB after; both consumed by layer-2 GEMMs (stream order).
    u16* y1bf = (u16*)d_out;
    u16* Xbf  = (u16*)((char*)d_out + 33554432);

    char* ws = (char*)d_ws;
    size_t off = 0;
    auto alloc = [&](size_t bytes) { char* p = ws + off; off = (off + bytes + 255) & ~(size_t)255; return p; };
    u16*  Wt1f  = (u16*)alloc(2048ull * 512 * 2);
    u16*  Wt1b  = (u16*)alloc(2048ull * 512 * 2);
    u16*  Wt2f  = (u16*)alloc(2048ull * 1024 * 2);
    u16*  Wt2b  = (u16*)alloc(2048ull * 1024 * 2);
    u16*  Ut1f  = (u16*)alloc(2048ull * 512 * 2);
    u16*  Ut1b  = (u16*)alloc(2048ull * 512 * 2);
    u16*  Ut2f  = (u16*)alloc(2048ull * 512 * 2);
    u16*  Ut2b  = (u16*)alloc(2048ull * 512 * 2);
    int*  maskb = (int*)alloc(16384ull * 4);
    // flags (64 u32, padded to 1 KB) + h exchange (2 slots x 2 dirs x 64 x 512 bf16 =
    // 256 KB), contiguous so one init kernel zeroes both.
    u32*  flags = (u32*)alloc(1024);
    u16*  hg    = (u16*)alloc(2ull * 2 * 64 * 512 * 2);
    _Float16* xzf = (_Float16*)alloc(16384ull * 2048 * 2);
    _Float16* xzb = (_Float16*)alloc(16384ull * 2048 * 2);
    (void)ws_size; (void)in_sizes; (void)n_in; (void)out_size;
    const int initN = (1024 + 262144) / 4;

    // prep
    mask_kernel<<<dim3(16384), dim3(64), 0, stream>>>(X, maskb);
    cast_bf16_kernel<<<dim3(8192), dim3(256), 0, stream>>>(X, Xbf, 16384 * 512);
    transpose_cast_kernel<<<dim3(64, 16), dim3(32, 8), 0, stream>>>(Wf1, Wt1f, 512, 2048);
    transpose_cast_kernel<<<dim3(64, 16), dim3(32, 8), 0, stream>>>(Wb1, Wt1b, 512, 2048);
    transpose_cast_kernel<<<dim3(64, 32), dim3(32, 8), 0, stream>>>(Wf2, Wt2f, 1024, 2048);
    transpose_cast_kernel<<<dim3(64, 32), dim3(32, 8), 0, stream>>>(Wb2, Wt2b, 1024, 2048);
    transpose_cast_kernel<<<dim3(64, 16), dim3(32, 8), 0, stream>>>(Uf1, Ut1f, 512, 2048);
    transpose_cast_kernel<<<dim3(64, 16), dim3(32, 8), 0, stream>>>(Ub1, Ut1b, 512, 2048);
    transpose_cast_kernel<<<dim3(64, 16), dim3(32, 8), 0, stream>>>(Uf2, Ut2f, 512, 2048);
    transpose_cast_kernel<<<dim3(64, 16), dim3(32, 8), 0, stream>>>(Ub2, Ut2b, 512, 2048);

    // layer 1
    gemm_xz_kernel<<<dim3(256, 32), dim3(256), 0, stream>>>(Xbf, Wt1f, bf1, xzf, 512);
    gemm_xz_kernel<<<dim3(256, 32), dim3(256), 0, stream>>>(Xbf, Wt1b, bb1, xzb, 512);
    init_rec_kernel<<<dim3((initN + 255) / 256), dim3(256), 0, stream>>>(flags, initN);
    lstm_rec7_kernel<<<dim3(32, 2), dim3(256), 0, stream>>>(
        xzf, xzb, Ut1f, Ut1b, maskb, flags, hg, y1bf, nullptr, nullptr);

    // layer 2
    gemm_xz_kernel<<<dim3(256, 32), dim3(256), 0, stream>>>(y1bf, Wt2f, bf2, xzf, 1024);
    gemm_xz_kernel<<<dim3(256, 32), dim3(256), 0, stream>>>(y1bf, Wt2b, bb2, xzb, 1024);
    init_rec_kernel<<<dim3((initN + 255) / 256), dim3(256), 0, stream>>>(flags, initN);
    lstm_rec7_kernel<<<dim3(32, 2), dim3(256), 0, stream>>>(
        xzf, xzb, Ut2f, Ut2b, maskb, flags, hg, nullptr, out, out + 16777216);
}

// Round 9
// 5177.683 us; speedup vs baseline: 6.3050x; 1.1320x over previous
//
#include <hip/hip_runtime.h>

typedef unsigned short u16;
typedef unsigned int u32;
typedef unsigned long long u64;
typedef __attribute__((ext_vector_type(8))) short bf16x8;
typedef __attribute__((ext_vector_type(4))) float f32x4;
typedef __attribute__((ext_vector_type(4))) _Float16 f16x4;

#define MFMA16(a, b, c) __builtin_amdgcn_mfma_f32_16x16x32_bf16((a), (b), (c), 0, 0, 0)

__device__ __forceinline__ u16 f2bf(float f) {
    union { float f; u32 u; } v; v.f = f;
    u32 r = v.u + 0x7FFFu + ((v.u >> 16) & 1u);
    return (u16)(r >> 16);
}
__device__ __forceinline__ float sigmoidf_(float x) {
    return 1.0f / (1.0f + __expf(-x));
}
__device__ __forceinline__ float tanhf_(float x) {
    float e = __expf(-2.0f * x);
    return (1.0f - e) / (1.0f + e);
}

// ---------------- mask: mask[row] = any(X[row, :512] != 0) ----------------
__global__ void mask_kernel(const float* __restrict__ X, int* __restrict__ mask) {
    int row = blockIdx.x;
    int lane = threadIdx.x;
    const float* r = X + (size_t)row * 512;
    int nz = 0;
    #pragma unroll
    for (int i = 0; i < 8; ++i) nz |= (r[lane + 64 * i] != 0.0f);
    nz = __any(nz);
    if (lane == 0) mask[row] = nz ? 1 : 0;
}

// ---------------- cast fp32 -> bf16 (4 elems/thread) ----------------
__global__ void cast_bf16_kernel(const float* __restrict__ in, u16* __restrict__ out, int n) {
    int i = (blockIdx.x * blockDim.x + threadIdx.x) * 4;
    if (i + 3 < n) {
        float4 v = *(const float4*)(in + i);
        u32 a = (u32)f2bf(v.x) | ((u32)f2bf(v.y) << 16);
        u32 b = (u32)f2bf(v.z) | ((u32)f2bf(v.w) << 16);
        *(uint2*)(out + i) = make_uint2(a, b);
    }
}

// ---------------- transpose + cast: in fp32 [K][N] -> out bf16 [N][K] ----------------
__global__ void transpose_cast_kernel(const float* __restrict__ in, u16* __restrict__ out,
                                      int K, int N) {
    __shared__ float tile[32][33];
    int k0 = blockIdx.y * 32, n0 = blockIdx.x * 32;
    int tx = threadIdx.x, ty = threadIdx.y;
    #pragma unroll
    for (int i = ty; i < 32; i += 8)
        tile[i][tx] = in[(size_t)(k0 + i) * N + (n0 + tx)];
    __syncthreads();
    #pragma unroll
    for (int i = ty; i < 32; i += 8)
        out[(size_t)(n0 + i) * K + (k0 + tx)] = f2bf(tile[tx][i]);
}

// ---------------- GEMM: xz = A @ Bt^T + bias, output in rec-friendly layout ----------
// C element index: (((t*32 + slice)*64 + b)*16 + dcol)*4 + g   (fp16)
// where m-row = b*256+t, n-col = g*512 + slice*16 + dcol.
__global__ __launch_bounds__(256) void gemm_xz_kernel(
        const u16* __restrict__ A, const u16* __restrict__ Bt,
        const float* __restrict__ bias, _Float16* __restrict__ C, int K) {
    int w = threadIdx.x >> 6, lane = threadIdx.x & 63;
    int q = lane >> 4, col = lane & 15;
    int m0 = blockIdx.x * 64 + w * 16;
    int n0 = blockIdx.y * 64;

    const u16* arow = A + (size_t)(m0 + col) * K + q * 8;
    f32x4 acc[4];
    #pragma unroll
    for (int nt = 0; nt < 4; ++nt) acc[nt] = (f32x4){0.f, 0.f, 0.f, 0.f};

    for (int kc = 0; kc < K; kc += 32) {
        bf16x8 a = *(const bf16x8*)(arow + kc);
        #pragma unroll
        for (int nt = 0; nt < 4; ++nt) {
            bf16x8 b = *(const bf16x8*)(Bt + (size_t)(n0 + nt * 16 + col) * K + kc + q * 8);
            acc[nt] = MFMA16(a, b, acc[nt]);
        }
    }
    #pragma unroll
    for (int nt = 0; nt < 4; ++nt) {
        int n = n0 + nt * 16 + col;
        int g = n >> 9, d = n & 511;
        float bs = bias[n];
        #pragma unroll
        for (int r = 0; r < 4; ++r) {
            int row = m0 + q * 4 + r;
            int b = row >> 8, t = row & 255;
            size_t idx = ((((size_t)t * 32 + (d >> 4)) * 64 + b) * 16 + (d & 15)) * 4 + g;
            C[idx] = (_Float16)(acc[nt][r] + bs);
        }
    }
}

// ---------------- zero-init (flags + h exchange buffers) ----------------
__global__ void init_rec_kernel(u32* __restrict__ p, int n) {
    int i = blockIdx.x * 256 + threadIdx.x;
    if (i < n) p[i] = 0;
}

// ---------------- persistent d-sliced LSTM recurrence, v8 ----------------
// grid (32 slices, 2 dirs) x 256 thr (4 waves). Block owns 16 h-dims x 4 gates.
// U-slice in LDS, per-fragment contiguous (conflict-free).
// R9 A/B: fence-free publish (R6 protocol, afr-stride-fixed). h published via
//   shfl-packed u32 relaxed AGENT atomic stores (sc1 write-through -> ACK at
//   coherence point), then s_waitcnt vmcnt(0) + __syncthreads (all waves' h at
//   LLC), then thread0 fire-and-forget relaxed AGENT flag store. NO buffer_wbl2,
//   NO RMW round-trip, NO buffer_inv anywhere.
//   [R6's apparent falsification of this protocol is void: its failure was the
//    afr u64 stride bug (R7 bit-identical fingerprint), fixed in R8.]
// Consume: relaxed AGENT polls of 32 flags, then relaxed AGENT u64 loads of h
//   (LLC-coherent). Double-buffer safety: flag>=k certifies h^k written (data-dep
//   on consuming h^{k-1}); slot overwrite only after all flags >= k.
__global__ __launch_bounds__(256) void lstm_rec8_kernel(
        const _Float16* __restrict__ xz_f, const _Float16* __restrict__ xz_b,
        const u16* __restrict__ Ut_f, const u16* __restrict__ Ut_b,
        const int* __restrict__ mask,
        u32* __restrict__ flags,    // [dir*32 + slice] monotone step counters
        u16* __restrict__ hg,       // [slot][dir][64][512] bf16, slot stride 65536
        u16* __restrict__ y_bf,     // layer1 out (null for layer2)
        float* __restrict__ y_f32,  // layer2 H out (null for layer1)
        float* __restrict__ hc_out) // layer2 hidden @0, cell @65536 (null for layer1)
{
    const int T = 256;
    int slice = blockIdx.x, dir = blockIdx.y;
    int tid = threadIdx.x;
    int lane = tid & 63, q = lane >> 4, col = lane & 15;
    int ds = slice * 16, m0 = (tid >> 6) * 16;

    const _Float16* xz = dir ? xz_b : xz_f;
    const u16* Ut = dir ? Ut_b : Ut_f;
    u32* dirflags = flags + dir * 32;
    u32* myflag = dirflags + slice;

    // ---- stage U-slice into LDS once, per-fragment contiguous ----
    // cell = (g*16+kc)*64 + l; holds U[g*512+ds+(l&15)][kc*32+(l>>4)*8 ..+8].
    alignas(16) __shared__ u16 Ulds[4 * 16 * 64 * 8];  // 64 KB
    for (int cell = tid; cell < 4096; cell += 256) {
        int l = cell & 63, fr = cell >> 6;
        int kc = fr & 15, g = fr >> 4;
        *(uint4*)&Ulds[cell * 8] =
            *(const uint4*)(Ut + (size_t)(g * 512 + ds + (l & 15)) * 512 + kc * 32 + (l >> 4) * 8);
    }

    float creg[4] = {0.f, 0.f, 0.f, 0.f};
    float hreg[4] = {0.f, 0.f, 0.f, 0.f};
    __syncthreads();

    for (int it = 0; it < T; ++it) {
        int t = dir ? (T - 1 - it) : it;
        const u16* hsrc = hg + (it & 1) * 65536 + dir * 32768;
        u16* hdst = hg + ((it & 1) ^ 1) * 65536 + dir * 32768;

        // xz + mask loads for this step (independent of h) — issued before the poll
        f16x4 xzv[4];
        {
            const _Float16* xzt = xz + (((size_t)t * 32 + slice) * 64) * 64;
            #pragma unroll
            for (int r = 0; r < 4; ++r)
                xzv[r] = *(const f16x4*)(xzt + ((m0 + q * 4 + r) * 16 + col) * 4);
        }
        int mk[4];
        #pragma unroll
        for (int r = 0; r < 4; ++r) mk[r] = mask[(m0 + q * 4 + r) * T + t];

        // ---- wait for all 32 producer blocks of this dir to publish h^{it} ----
        if (it) {
            u32 tgt = (u32)it;
            for (;;) {
                u32 f = __hip_atomic_load(dirflags + (lane & 31), __ATOMIC_RELAXED,
                                          __HIP_MEMORY_SCOPE_AGENT);
                if (__all(f >= tgt)) break;
                __builtin_amdgcn_s_sleep(1);
            }
            __builtin_amdgcn_sched_barrier(0);  // pin h loads after the poll
        }

        // ---- a-fragments of h^{it} via relaxed agent u64 loads (LLC-coherent) ----
        // chunk c covers k = c*32 + q*8 .. +8  (32 u16 = 8 u64 stride)
        bf16x8 afr[16];
        {
            const u64* hp = (const u64*)(hsrc + (size_t)(m0 + col) * 512 + q * 8);
            #pragma unroll
            for (int c = 0; c < 16; ++c) {
                union { u64 qw[2]; bf16x8 v; } u;
                u.qw[0] = __hip_atomic_load(hp + c * 8, __ATOMIC_RELAXED,
                                            __HIP_MEMORY_SCOPE_AGENT);
                u.qw[1] = __hip_atomic_load(hp + c * 8 + 1, __ATOMIC_RELAXED,
                                            __HIP_MEMORY_SCOPE_AGENT);
                afr[c] = u.v;
            }
        }

        // ---- z = h @ U for 4 gates x 16 dims x wave's 16 rows ----
        f32x4 acc[4];
        #pragma unroll
        for (int g = 0; g < 4; ++g) acc[g] = (f32x4){0.f, 0.f, 0.f, 0.f};
        #pragma unroll
        for (int kc = 0; kc < 16; ++kc) {
            #pragma unroll
            for (int g = 0; g < 4; ++g) {
                bf16x8 b = *(const bf16x8*)&Ulds[((g * 16 + kc) * 64 + lane) * 8];
                acc[g] = MFMA16(afr[kc], b, acc[g]);
            }
        }

        // ---- gates, state update, y stores ----
        u32 hbv[4];
        #pragma unroll
        for (int r = 0; r < 4; ++r) {
            int b = m0 + q * 4 + r;
            float zi = acc[0][r] + (float)xzv[r][0];
            float zf = acc[1][r] + (float)xzv[r][1];
            float zg = acc[2][r] + (float)xzv[r][2];
            float zo = acc[3][r] + (float)xzv[r][3];
            float ig = sigmoidf_(zi);
            float fg = sigmoidf_(zf);
            float gg = tanhf_(zg);
            float og = sigmoidf_(zo);
            float cn = fg * creg[r] + ig * gg;
            float hn = og * tanhf_(cn);
            if (mk[r]) { creg[r] = cn; hreg[r] = hn; }
            hbv[r] = (u32)f2bf(hreg[r]);
            size_t ybase = ((size_t)b * T + t) * 1024 + dir * 512 + ds + col;
            if (y_bf) __builtin_nontemporal_store((u16)hbv[r], y_bf + ybase);
            else      __builtin_nontemporal_store(hreg[r], y_f32 + ybase);
        }

        // ---- publish h: pack dim pairs via shfl, write-through u32 agent stores ----
        // even col lanes store rows q*4+{0,1}; odd col lanes rows q*4+{2,3};
        // low u16 of the packed word = even dim (verified mapping).
        {
            u32 part[4];
            #pragma unroll
            for (int r = 0; r < 4; ++r) part[r] = (u32)__shfl_xor((int)hbv[r], 1);
            int odd = col & 1;
            u32 p0 = odd ? (part[2] | (hbv[2] << 16)) : (hbv[0] | (part[0] << 16));
            u32 p1 = odd ? (part[3] | (hbv[3] << 16)) : (hbv[1] | (part[1] << 16));
            int r0 = q * 4 + (odd ? 2 : 0);
            u32* w0 = (u32*)(hdst + (size_t)(m0 + r0) * 512 + ds + (col & ~1));
            u32* w1 = (u32*)(hdst + (size_t)(m0 + r0 + 1) * 512 + ds + (col & ~1));
            __hip_atomic_store(w0, p0, __ATOMIC_RELAXED, __HIP_MEMORY_SCOPE_AGENT);
            __hip_atomic_store(w1, p1, __ATOMIC_RELAXED, __HIP_MEMORY_SCOPE_AGENT);
        }

        // ---- drain WT store ACKs (all waves), then fire-and-forget flag ----
        asm volatile("s_waitcnt vmcnt(0) lgkmcnt(0)" ::: "memory");
        __syncthreads();
        if (tid == 0)
            __hip_atomic_store(myflag, (u32)(it + 1), __ATOMIC_RELAXED,
                               __HIP_MEMORY_SCOPE_AGENT);
    }

    if (hc_out) {
        #pragma unroll
        for (int r = 0; r < 4; ++r) {
            int b = m0 + q * 4 + r;
            hc_out[(size_t)b * 1024 + dir * 512 + ds + col] = hreg[r];
            hc_out[65536 + (size_t)b * 1024 + dir * 512 + ds + col] = creg[r];
        }
    }
}

extern "C" void kernel_launch(void* const* d_in, const int* in_sizes, int n_in,
                              void* d_out, int out_size, void* d_ws, size_t ws_size,
                              hipStream_t stream) {
    const float* X   = (const float*)d_in[0];
    const float* Wf1 = (const float*)d_in[1];
    const float* Uf1 = (const float*)d_in[2];
    const float* bf1 = (const float*)d_in[3];
    const float* Wb1 = (const float*)d_in[4];
    const float* Ub1 = (const float*)d_in[5];
    const float* bb1 = (const float*)d_in[6];
    const float* Wf2 = (const float*)d_in[7];
    const float* Uf2 = (const float*)d_in[8];
    const float* bf2 = (const float*)d_in[9];
    const float* Wb2 = (const float*)d_in[10];
    const float* Ub2 = (const float*)d_in[11];
    const float* bb2 = (const float*)d_in[12];
    float* out = (float*)d_out;

    // scratch carved from d_out's H region (67.1 MB, dead until layer-2 rec):
    // y1bf 33.55 MB @0, Xbf 16.78 MB after; both consumed by layer-2 GEMMs (stream order).
    u16* y1bf = (u16*)d_out;
    u16* Xbf  = (u16*)((char*)d_out + 33554432);

    char* ws = (char*)d_ws;
    size_t off = 0;
    auto alloc = [&](size_t bytes) { char* p = ws + off; off = (off + bytes + 255) & ~(size_t)255; return p; };
    u16*  Wt1f  = (u16*)alloc(2048ull * 512 * 2);
    u16*  Wt1b  = (u16*)alloc(2048ull * 512 * 2);
    u16*  Wt2f  = (u16*)alloc(2048ull * 1024 * 2);
    u16*  Wt2b  = (u16*)alloc(2048ull * 1024 * 2);
    u16*  Ut1f  = (u16*)alloc(2048ull * 512 * 2);
    u16*  Ut1b  = (u16*)alloc(2048ull * 512 * 2);
    u16*  Ut2f  = (u16*)alloc(2048ull * 512 * 2);
    u16*  Ut2b  = (u16*)alloc(2048ull * 512 * 2);
    int*  maskb = (int*)alloc(16384ull * 4);
    // flags (64 u32, padded to 1 KB) + h exchange (2 slots x 2 dirs x 64 x 512 bf16 =
    // 256 KB), contiguous so one init kernel zeroes both.
    u32*  flags = (u32*)alloc(1024);
    u16*  hg    = (u16*)alloc(2ull * 2 * 64 * 512 * 2);
    _Float16* xzf = (_Float16*)alloc(16384ull * 2048 * 2);
    _Float16* xzb = (_Float16*)alloc(16384ull * 2048 * 2);
    (void)ws_size; (void)in_sizes; (void)n_in; (void)out_size;
    const int initN = (1024 + 262144) / 4;

    // prep
    mask_kernel<<<dim3(16384), dim3(64), 0, stream>>>(X, maskb);
    cast_bf16_kernel<<<dim3(8192), dim3(256), 0, stream>>>(X, Xbf, 16384 * 512);
    transpose_cast_kernel<<<dim3(64, 16), dim3(32, 8), 0, stream>>>(Wf1, Wt1f, 512, 2048);
    transpose_cast_kernel<<<dim3(64, 16), dim3(32, 8), 0, stream>>>(Wb1, Wt1b, 512, 2048);
    transpose_cast_kernel<<<dim3(64, 32), dim3(32, 8), 0, stream>>>(Wf2, Wt2f, 1024, 2048);
    transpose_cast_kernel<<<dim3(64, 32), dim3(32, 8), 0, stream>>>(Wb2, Wt2b, 1024, 2048);
    transpose_cast_kernel<<<dim3(64, 16), dim3(32, 8), 0, stream>>>(Uf1, Ut1f, 512, 2048);
    transpose_cast_kernel<<<dim3(64, 16), dim3(32, 8), 0, stream>>>(Ub1, Ut1b, 512, 2048);
    transpose_cast_kernel<<<dim3(64, 16), dim3(32, 8), 0, stream>>>(Uf2, Ut2f, 512, 2048);
    transpose_cast_kernel<<<dim3(64, 16), dim3(32, 8), 0, stream>>>(Ub2, Ut2b, 512, 2048);

    // layer 1
    gemm_xz_kernel<<<dim3(256, 32), dim3(256), 0, stream>>>(Xbf, Wt1f, bf1, xzf, 512);
    gemm_xz_kernel<<<dim3(256, 32), dim3(256), 0, stream>>>(Xbf, Wt1b, bb1, xzb, 512);
    init_rec_kernel<<<dim3((initN + 255) / 256), dim3(256), 0, stream>>>(flags, initN);
    lstm_rec8_kernel<<<dim3(32, 2), dim3(256), 0, stream>>>(
        xzf, xzb, Ut1f, Ut1b, maskb, flags, hg, y1bf, nullptr, nullptr);

    // layer 2
    gemm_xz_kernel<<<dim3(256, 32), dim3(256), 0, stream>>>(y1bf, Wt2f, bf2, xzf, 1024);
    gemm_xz_kernel<<<dim3(256, 32), dim3(256), 0, stream>>>(y1bf, Wt2b, bb2, xzb, 1024);
    init_rec_kernel<<<dim3((initN + 255) / 256), dim3(256), 0, stream>>>(flags, initN);
    lstm_rec8_kernel<<<dim3(32, 2), dim3(256), 0, stream>>>(
        xzf, xzb, Ut2f, Ut2b, maskb, flags, hg, nullptr, out, out + 16777216);
}